// Round 12
// baseline (1288.206 us; speedup 1.0000x reference)
//
#include <hip/hip_runtime.h>
#include <hip/hip_bf16.h>

// Fused transformer block as a 3-kernel pipeline:
//   prep_w     : f32 weights -> bf16 transposed in ws (1.5 MB only).
//   attnproj_k : LN1 -> per-head (QKV -> causal softmax -> PV -> proj-accum
//                in regs) -> x2 = x + sa + bproj -> f32 in d_out. Proven R9.
//   mlp_k      : R9 structure (2 batch/block, M=128, 8 waves, 4 N-chunks,
//                16x16x32 MFMA -- proven numerics) + REGISTER WEIGHT PREFETCH:
//                the bar() "memory" clobber blocks compiler hoisting of global
//                loads across barriers, so W2-frags (this chunk) and W1-frags
//                (next chunk) are manually loaded into regs BEFORE the
//                barrier; their latency hides under the barrier + LDS phase.
// R11 lesson: 32x32 MFMA needs 16-aligned C/D tuples which inline-asm "v"
// can't guarantee -> silent corruption. Stay on proven 4-reg 16x16 path.
// ws layout (bf16/ushort): [0,65536) WqT[h][d][c]; [65536,131072) WkT;
// [131072,196608) WvT; [196608,262144) WprojT[n][c]; [262144,524288) W1T[n][c];
// [524288,786432) W2T[n][k].  Requires ws_size >= 1572864 bytes only.

typedef float v4f __attribute__((ext_vector_type(4)));
typedef int   v4i __attribute__((ext_vector_type(4)));
typedef float f4v __attribute__((ext_vector_type(4)));
typedef unsigned long long u64;

#define DEV static __device__ __forceinline__

DEV unsigned short f2bf(float f){
  return __builtin_bit_cast(unsigned short, __float2bfloat16(f));
}

// lgkm-only workgroup barrier: orders LDS traffic, leaves global loads in
// flight. Safe because all cross-wave data in these kernels flows via LDS.
DEV void bar(){
  asm volatile("s_waitcnt lgkmcnt(0)\n\ts_barrier" ::: "memory");
}

// bf16 MFMA via inline asm (layout-safe: consistent per-lane contiguous-8 K).
DEV v4f mfma16(v4i a, v4i b, v4f c){
  asm("v_mfma_f32_16x16x32_bf16 %0, %1, %2, %0" : "+v"(c) : "v"(a), "v"(b));
  return c;
}
DEV v4f accfence(v4f c){
  asm("s_nop 7\n\ts_nop 3" : "+v"(c));
  return c;
}

// Swizzled LDS byte offsets (XOR row bits into 16B-granule bits).
DEV int hoff(int r, int c){ return r*512 + ((c*2) ^ ((r & 7) << 4)); }  // [*][256] bf16
DEV int koff(int r, int c){ return r*128 + ((c*2) ^ ((r & 7) << 4)); }  // [*][64]  bf16

DEV u64 pack4(v4f v){
  return (u64)f2bf(v[0]) | ((u64)f2bf(v[1]) << 16)
       | ((u64)f2bf(v[2]) << 32) | ((u64)f2bf(v[3]) << 48);
}

DEV float rsum64(float v){
  #pragma unroll
  for (int k = 1; k < 64; k <<= 1) v += __shfl_xor(v, k);
  return v;
}
DEV float rsum16(float v){
  #pragma unroll
  for (int k = 1; k < 16; k <<= 1) v += __shfl_xor(v, k);
  return v;
}
DEV float rmax16(float v){
  #pragma unroll
  for (int k = 1; k < 16; k <<= 1) v = fmaxf(v, __shfl_xor(v, k));
  return v;
}

__global__ void prep_w(const float* __restrict__ Wq, const float* __restrict__ Wk,
                       const float* __restrict__ Wv, const float* __restrict__ Wp,
                       const float* __restrict__ W1, const float* __restrict__ W2,
                       unsigned short* __restrict__ ws){
  int t = blockIdx.x * 256 + threadIdx.x;   // grid covers exactly 786432
  float v;
  if (t < 196608){
    int seg = t >> 16, r = t & 65535;
    int c = r & 255, d = (r >> 8) & 63, h = r >> 14;
    const float* W = (seg == 0) ? Wq : ((seg == 1) ? Wk : Wv);
    v = W[h*16384 + c*64 + d];
  } else if (t < 262144){
    int r = t - 196608; int n = r >> 8, c = r & 255;
    v = Wp[c*256 + n];
  } else if (t < 524288){
    int r = t - 262144; int n = r >> 8, c = r & 255;
    v = W1[c*1024 + n];
  } else {
    int r = t - 524288; int n = r >> 10, k = r & 1023;
    v = W2[k*256 + n];
  }
  ws[t] = f2bf(v);
}

// ---------------- attnproj_k: LN1 + attention + proj + residual --------------
// One 4-wave block per batch element; proven numerics, unchanged from R9.
__global__ __launch_bounds__(256, 2) void attnproj_k(
    const float* __restrict__ x,
    const float* __restrict__ ln1g, const float* __restrict__ ln1b,
    const unsigned short* __restrict__ wqT,
    const unsigned short* __restrict__ wkT,
    const unsigned short* __restrict__ wvT,
    const unsigned short* __restrict__ wpT,
    const float* __restrict__ bpj,
    float* __restrict__ outp)
{
  __shared__ char smb[65536] __attribute__((aligned(16)));
  char* sm = smb;
  const int HLS = 0, QLS = 32768, KLS = 40960, VTLS = 49152, PATLS = 57344;

  const int b = blockIdx.x;
  const float* __restrict__ xb = x + (size_t)b * 16384;
  float* __restrict__ ob = outp + (size_t)b * 16384;
  const int tid = threadIdx.x;
  const int w = tid >> 6, l = tid & 63, m = l & 15, g = l >> 4;
  const v4f zf = {0.f, 0.f, 0.f, 0.f};

  // Phase A: LN1 -> h (bf16, LDS), 16 rows/wave
  {
    f4v lg = *(const f4v*)(ln1g + 4*l);
    f4v lb = *(const f4v*)(ln1b + 4*l);
    #pragma unroll
    for (int rr = 0; rr < 16; ++rr){
      int r = w*16 + rr;
      f4v xv = *(const f4v*)(xb + r*256 + 4*l);
      float s = xv[0]+xv[1]+xv[2]+xv[3];
      float q = xv[0]*xv[0]+xv[1]*xv[1]+xv[2]*xv[2]+xv[3]*xv[3];
      s = rsum64(s); q = rsum64(q);
      float mu = s * (1.f/256.f);
      float rs = rsqrtf(q * (1.f/256.f) - mu*mu + 1e-6f);
      u64 pk = 0;
      #pragma unroll
      for (int j = 0; j < 4; ++j){
        float hv = (xv[j] - mu) * rs * lg[j] + lb[j];
        pk |= (u64)f2bf(hv) << (16*j);
      }
      *(u64*)(sm + HLS + hoff(r, 4*l)) = pk;
    }
  }
  bar();

  // Phase B: attention; sa accumulated in regs
  v4f sa[4][4];
  #pragma unroll
  for (int i = 0; i < 4; ++i){
    #pragma unroll
    for (int j = 0; j < 4; ++j) sa[i][j] = zf;
  }

  #pragma unroll 1
  for (int hh = 0; hh < 4; ++hh){
    // QKV: wave w owns cols w*16..w*16+15 of q,k,v (shared A-fragments)
    {
      const unsigned short* bq = wqT + hh*16384 + (w*16 + m)*256;
      const unsigned short* bk = wkT + hh*16384 + (w*16 + m)*256;
      const unsigned short* bv = wvT + hh*16384 + (w*16 + m)*256;
      v4f qa[4] = {zf,zf,zf,zf}, ka[4] = {zf,zf,zf,zf}, va[4] = {zf,zf,zf,zf};
      #pragma unroll
      for (int ks = 0; ks < 8; ++ks){
        int k0 = ks*32 + 8*g;
        v4i bq4 = *(const v4i*)(bq + k0);
        v4i bk4 = *(const v4i*)(bk + k0);
        v4i bv4 = *(const v4i*)(bv + k0);
        #pragma unroll
        for (int rt = 0; rt < 4; ++rt){
          v4i af = *(const v4i*)(sm + HLS + hoff(rt*16 + m, k0));
          qa[rt] = mfma16(af, bq4, qa[rt]);
          ka[rt] = mfma16(af, bk4, ka[rt]);
          va[rt] = mfma16(af, bv4, va[rt]);
        }
      }
      #pragma unroll
      for (int rt = 0; rt < 4; ++rt){
        qa[rt] = accfence(qa[rt]); ka[rt] = accfence(ka[rt]); va[rt] = accfence(va[rt]);
        #pragma unroll
        for (int j = 0; j < 4; ++j){
          *(unsigned short*)(sm + QLS + koff(rt*16 + 4*g + j, w*16 + m)) = f2bf(qa[rt][j]);
          *(unsigned short*)(sm + KLS + koff(rt*16 + 4*g + j, w*16 + m)) = f2bf(ka[rt][j]);
        }
        *(u64*)(sm + VTLS + koff(w*16 + m, rt*16 + 4*g)) = pack4(va[rt]);  // V^T
      }
    }
    bar();   // bar1: q,k,v^T ready; prev-head PATLS readers done

    // S = Q K^T (stripe rows w*16..+15) -> softmax -> P -> PV -> own PATLS
    {
      v4f s4[4] = {zf,zf,zf,zf};
      #pragma unroll
      for (int ks = 0; ks < 2; ++ks){
        int k0 = ks*32 + 8*g;
        v4i qf = *(const v4i*)(sm + QLS + koff(w*16 + m, k0));
        #pragma unroll
        for (int nt = 0; nt < 4; ++nt){
          v4i kf = *(const v4i*)(sm + KLS + koff(nt*16 + m, k0));
          s4[nt] = mfma16(qf, kf, s4[nt]);
        }
      }
      #pragma unroll
      for (int nt = 0; nt < 4; ++nt) s4[nt] = accfence(s4[nt]);
      float mx[4] = {-3e38f, -3e38f, -3e38f, -3e38f};
      #pragma unroll
      for (int nt = 0; nt < 4; ++nt){
        #pragma unroll
        for (int j = 0; j < 4; ++j){
          int t = w*16 + 4*g + j, ss = nt*16 + m;
          float z = s4[nt][j] * 0.125f;
          z = (ss <= t) ? z : -1e30f;
          s4[nt][j] = z;
          mx[j] = fmaxf(mx[j], z);
        }
      }
      #pragma unroll
      for (int j = 0; j < 4; ++j) mx[j] = rmax16(mx[j]);
      float sum[4] = {0.f, 0.f, 0.f, 0.f};
      #pragma unroll
      for (int nt = 0; nt < 4; ++nt){
        #pragma unroll
        for (int j = 0; j < 4; ++j){
          float p = __expf(s4[nt][j] - mx[j]);
          s4[nt][j] = p;
          sum[j] += p;
        }
      }
      #pragma unroll
      for (int j = 0; j < 4; ++j) sum[j] = 1.f / rsum16(sum[j]);
      #pragma unroll
      for (int nt = 0; nt < 4; ++nt){
        #pragma unroll
        for (int j = 0; j < 4; ++j)
          *(unsigned short*)(sm + PATLS + w*2048 + koff(4*g + j, nt*16 + m)) =
              f2bf(s4[nt][j] * sum[j]);
      }
      v4f av[4] = {zf,zf,zf,zf};
      #pragma unroll
      for (int ks = 0; ks < 2; ++ks){
        int k0 = ks*32 + 8*g;
        v4i pf = *(const v4i*)(sm + PATLS + w*2048 + koff(m, k0));
        #pragma unroll
        for (int nt = 0; nt < 4; ++nt){
          v4i vf = *(const v4i*)(sm + VTLS + koff(nt*16 + m, k0));
          av[nt] = mfma16(pf, vf, av[nt]);
        }
      }
      #pragma unroll
      for (int nt = 0; nt < 4; ++nt) av[nt] = accfence(av[nt]);
      #pragma unroll
      for (int nt = 0; nt < 4; ++nt){
        #pragma unroll
        for (int j = 0; j < 4; ++j)
          *(unsigned short*)(sm + PATLS + w*2048 + koff(4*g + j, nt*16 + m)) =
              f2bf(av[nt][j]);
      }
    }
    bar();   // bar2: att stripes ready

    // proj: sa += att_head @ Wproj[64*hh:, :]; wave w owns cols w*64..w*64+63
    #pragma unroll
    for (int ks = 0; ks < 2; ++ks){
      int k0 = ks*32 + 8*g;
      v4i af2[4];
      #pragma unroll
      for (int rt = 0; rt < 4; ++rt)
        af2[rt] = *(const v4i*)(sm + PATLS + rt*2048 + koff(m, k0));
      #pragma unroll
      for (int nt = 0; nt < 4; ++nt){
        v4i bp = *(const v4i*)(wpT + (w*64 + nt*16 + m)*256 + hh*64 + k0);
        #pragma unroll
        for (int rt = 0; rt < 4; ++rt) sa[rt][nt] = mfma16(af2[rt], bp, sa[rt][nt]);
      }
    }
    // no trailing barrier: PATLS next written after next bar1.
  }

  // Phase C residual: x2 = x + sa + bproj -> f32 in d_out
  {
    #pragma unroll
    for (int i = 0; i < 4; ++i){
      #pragma unroll
      for (int j = 0; j < 4; ++j) sa[i][j] = accfence(sa[i][j]);
    }
    float bp4[4];
    #pragma unroll
    for (int nt = 0; nt < 4; ++nt) bp4[nt] = bpj[w*64 + nt*16 + m];
    #pragma unroll
    for (int rt = 0; rt < 4; ++rt){
      #pragma unroll
      for (int j = 0; j < 4; ++j){
        int row = rt*16 + 4*g + j;
        #pragma unroll
        for (int nt = 0; nt < 4; ++nt){
          int col = w*64 + nt*16 + m;
          ob[row*256 + col] = xb[row*256 + col] + sa[rt][nt][j] + bp4[nt];
        }
      }
    }
  }
}

// ---------------- mlp_k: 2 batch/block (M=128), register weight prefetch -----
// LDS 128KB dynamic: h2 [128][256] bf16 @0 | act chunk [128][256] bf16 @64K.
// 8 waves; wave w owns 32 N-cols. 4 chunks x (GEMM1, prefetch W2+W1next,
// bar, GEMM2, bar). Weight frags live in regs across barriers (the bar()
// memory clobber otherwise pins their loads after the barrier).
#define MLP_LDS 131072
__global__ __launch_bounds__(512, 1) void mlp_k(
    const float* __restrict__ ln2g, const float* __restrict__ ln2b,
    const unsigned short* __restrict__ w1T,
    const float* __restrict__ b1,
    const unsigned short* __restrict__ w2T,
    const float* __restrict__ b2,
    float* __restrict__ outp)
{
  extern __shared__ char sm[];
  const int HLS = 0, ACT = 65536;
  const int bb = blockIdx.x;               // 2-batch slab
  float* __restrict__ ob = outp + (size_t)bb * 32768;
  const int tid = threadIdx.x;
  const int w = tid >> 6, l = tid & 63, m = l & 15, g = l >> 4;
  const v4f zf = {0.f, 0.f, 0.f, 0.f};

  // LN2 from x2 (f32 in d_out) -> h2 (bf16, LDS); 8 waves x 16 rows = 128
  {
    f4v lg = *(const f4v*)(ln2g + 4*l);
    f4v lb = *(const f4v*)(ln2b + 4*l);
    #pragma unroll
    for (int rr = 0; rr < 16; ++rr){
      int r = w*16 + rr;
      f4v xv = *(const f4v*)(ob + r*256 + 4*l);
      float s = xv[0]+xv[1]+xv[2]+xv[3];
      float q = xv[0]*xv[0]+xv[1]*xv[1]+xv[2]*xv[2]+xv[3]*xv[3];
      s = rsum64(s); q = rsum64(q);
      float mu = s * (1.f/256.f);
      float rs = rsqrtf(q * (1.f/256.f) - mu*mu + 1e-6f);
      u64 pk = 0;
      #pragma unroll
      for (int j = 0; j < 4; ++j){
        float hv = (xv[j] - mu) * rs * lg[j] + lb[j];
        pk |= (u64)f2bf(hv) << (16*j);
      }
      *(u64*)(sm + HLS + hoff(r, 4*l)) = pk;
    }
  }

  // Preload chunk 0's W1 fragments (before the LN2 barrier: latency hidden)
  v4i w1r[8][2];
  {
    const unsigned short* w1a = w1T + (0*256 + w*32 +      m)*256;
    const unsigned short* w1b = w1T + (0*256 + w*32 + 16 + m)*256;
    #pragma unroll
    for (int ks = 0; ks < 8; ++ks){
      int k0 = ks*32 + 8*g;
      w1r[ks][0] = *(const v4i*)(w1a + k0);
      w1r[ks][1] = *(const v4i*)(w1b + k0);
    }
  }
  bar();

  v4f ff[8][2];
  #pragma unroll
  for (int i = 0; i < 8; ++i){ ff[i][0] = zf; ff[i][1] = zf; }

  #pragma unroll 1
  for (int ch = 0; ch < 4; ++ch){
    // GEMM1: act[:, ch*256 + w*32 .. +31]; weights from regs (w1r)
    v4f a1[8][2];
    #pragma unroll
    for (int i = 0; i < 8; ++i){ a1[i][0] = zf; a1[i][1] = zf; }
    #pragma unroll
    for (int ks = 0; ks < 8; ++ks){
      int k0 = ks*32 + 8*g;
      #pragma unroll
      for (int rt = 0; rt < 8; ++rt){
        v4i af = *(const v4i*)(sm + HLS + hoff(rt*16 + m, k0));
        a1[rt][0] = mfma16(af, w1r[ks][0], a1[rt][0]);
        a1[rt][1] = mfma16(af, w1r[ks][1], a1[rt][1]);
      }
    }
    float b1v[2] = { b1[ch*256 + w*32 + m], b1[ch*256 + w*32 + 16 + m] };
    #pragma unroll
    for (int i = 0; i < 8; ++i){ a1[i][0] = accfence(a1[i][0]); a1[i][1] = accfence(a1[i][1]); }
    #pragma unroll
    for (int rt = 0; rt < 8; ++rt){
      #pragma unroll
      for (int j = 0; j < 4; ++j){
        int row = rt*16 + 4*g + j;
        #pragma unroll
        for (int nt = 0; nt < 2; ++nt){
          float v = fmaxf(a1[rt][nt][j] + b1v[nt], 0.f);
          *(unsigned short*)(sm + ACT + hoff(row, w*32 + nt*16 + m)) = f2bf(v);
        }
      }
    }

    // Prefetch W2 frags (this chunk) + W1 frags (next chunk) BEFORE the
    // barrier -- their ~L2 latency hides under bar + GEMM2's LDS phase.
    v4i w2r[8][2];
    {
      const unsigned short* w2a = w2T + (w*32 +      m)*1024 + ch*256;
      const unsigned short* w2b = w2T + (w*32 + 16 + m)*1024 + ch*256;
      #pragma unroll
      for (int ks = 0; ks < 8; ++ks){
        int k0 = ks*32 + 8*g;
        w2r[ks][0] = *(const v4i*)(w2a + k0);
        w2r[ks][1] = *(const v4i*)(w2b + k0);
      }
    }
    if (ch < 3){
      const unsigned short* w1a = w1T + ((ch+1)*256 + w*32 +      m)*256;
      const unsigned short* w1b = w1T + ((ch+1)*256 + w*32 + 16 + m)*256;
      #pragma unroll
      for (int ks = 0; ks < 8; ++ks){
        int k0 = ks*32 + 8*g;
        w1r[ks][0] = *(const v4i*)(w1a + k0);
        w1r[ks][1] = *(const v4i*)(w1b + k0);
      }
    }
    bar();   // act chunk ready

    // GEMM2: ff += act_chunk @ W2T[:, ch*256..]; weights from regs (w2r)
    #pragma unroll
    for (int ks = 0; ks < 8; ++ks){
      int k0 = ks*32 + 8*g;
      v4i af[8];
      #pragma unroll
      for (int rt = 0; rt < 8; ++rt)
        af[rt] = *(const v4i*)(sm + ACT + hoff(rt*16 + m, k0));
      #pragma unroll
      for (int nt = 0; nt < 2; ++nt){
        #pragma unroll
        for (int rt = 0; rt < 8; ++rt) ff[rt][nt] = mfma16(af[rt], w2r[ks][nt], ff[rt][nt]);
      }
    }
    bar();   // protect act before next chunk's GEMM1 overwrite
  }

  {
    float b2v[2] = { b2[w*32 + m], b2[w*32 + 16 + m] };
    #pragma unroll
    for (int i = 0; i < 8; ++i){ ff[i][0] = accfence(ff[i][0]); ff[i][1] = accfence(ff[i][1]); }
    #pragma unroll
    for (int rt = 0; rt < 8; ++rt){
      #pragma unroll
      for (int j = 0; j < 4; ++j){
        int row = rt*16 + 4*g + j;
        #pragma unroll
        for (int nt = 0; nt < 2; ++nt){
          int col = w*32 + nt*16 + m;
          ob[row*256 + col] += ff[rt][nt][j] + b2v[nt];
        }
      }
    }
  }
}

extern "C" void kernel_launch(void* const* d_in, const int* in_sizes, int n_in,
                              void* d_out, int out_size, void* d_ws, size_t ws_size,
                              hipStream_t stream) {
  const float* x    = (const float*)d_in[0];
  const float* ln1g = (const float*)d_in[1];
  const float* ln1b = (const float*)d_in[2];
  const float* Wq   = (const float*)d_in[3];
  const float* Wk   = (const float*)d_in[4];
  const float* Wv   = (const float*)d_in[5];
  const float* Wp   = (const float*)d_in[6];
  const float* bpj  = (const float*)d_in[7];
  const float* ln2g = (const float*)d_in[8];
  const float* ln2b = (const float*)d_in[9];
  const float* W1   = (const float*)d_in[10];
  const float* b1   = (const float*)d_in[11];
  const float* W2   = (const float*)d_in[12];
  const float* b2   = (const float*)d_in[13];
  unsigned short* ws = (unsigned short*)d_ws;
  float* outp = (float*)d_out;

  hipFuncSetAttribute((const void*)mlp_k,
                      hipFuncAttributeMaxDynamicSharedMemorySize, MLP_LDS);

  prep_w<<<3072, 256, 0, stream>>>(Wq, Wk, Wv, Wp, W1, W2, ws);
  attnproj_k<<<4096, 256, 0, stream>>>(x, ln1g, ln1b,
                                       ws, ws + 65536, ws + 131072, ws + 196608,
                                       bpj, outp);
  mlp_k<<<2048, 512, MLP_LDS, stream>>>(ln2g, ln2b, ws + 262144, b1,
                                        ws + 524288, b2, outp);
}

// Round 13
// 860.851 us; speedup vs baseline: 1.4964x; 1.4964x over previous
//
#include <hip/hip_runtime.h>
#include <hip/hip_bf16.h>

// Fused transformer block as a 3-kernel pipeline:
//   prep_w     : f32 weights -> bf16 transposed in ws (1.5 MB only).
//   attnproj_k : LN1 -> per-head (QKV -> causal softmax -> PV -> proj-accum
//                in regs) -> x2 = x + sa + bproj -> f32 in d_out. Proven R9.
//   mlp_k      : R9 structure (2 batch/block, M=128, 8 waves, 4 N-chunks,
//                8 lgkm barriers) with SWAPPED MFMA operands (A=weights,
//                B=activations): the j-register dim of the C-layout becomes
//                the output-COLUMN index, so act stores pack to ds_write_b64
//                (4x fewer LDS ops) and the final residual RMW is float4-
//                coalesced. Register-neutral vs R9 (a1 64 + ff 64 = 128).
// R12 lesson: the 128-VGPR live set is full; additive prefetch regs spill
// (FETCH 253->600MB). Improvements must be register-neutral.
// ws layout (bf16/ushort): [0,65536) WqT[h][d][c]; [65536,131072) WkT;
// [131072,196608) WvT; [196608,262144) WprojT[n][c]; [262144,524288) W1T[n][c];
// [524288,786432) W2T[n][k].  Requires ws_size >= 1572864 bytes only.

typedef float v4f __attribute__((ext_vector_type(4)));
typedef int   v4i __attribute__((ext_vector_type(4)));
typedef float f4v __attribute__((ext_vector_type(4)));
typedef unsigned long long u64;

#define DEV static __device__ __forceinline__

DEV unsigned short f2bf(float f){
  return __builtin_bit_cast(unsigned short, __float2bfloat16(f));
}

// lgkm-only workgroup barrier: orders LDS traffic, leaves global loads in
// flight. Safe because all cross-wave data in these kernels flows via LDS.
DEV void bar(){
  asm volatile("s_waitcnt lgkmcnt(0)\n\ts_barrier" ::: "memory");
}

// bf16 MFMA via inline asm (layout-safe: consistent per-lane contiguous-8 K).
DEV v4f mfma16(v4i a, v4i b, v4f c){
  asm("v_mfma_f32_16x16x32_bf16 %0, %1, %2, %0" : "+v"(c) : "v"(a), "v"(b));
  return c;
}
DEV v4f accfence(v4f c){
  asm("s_nop 7\n\ts_nop 3" : "+v"(c));
  return c;
}

// Swizzled LDS byte offsets (XOR row bits into 16B-granule bits).
DEV int hoff(int r, int c){ return r*512 + ((c*2) ^ ((r & 7) << 4)); }  // [*][256] bf16
DEV int koff(int r, int c){ return r*128 + ((c*2) ^ ((r & 7) << 4)); }  // [*][64]  bf16

DEV u64 pack4(v4f v){
  return (u64)f2bf(v[0]) | ((u64)f2bf(v[1]) << 16)
       | ((u64)f2bf(v[2]) << 32) | ((u64)f2bf(v[3]) << 48);
}

DEV float rsum64(float v){
  #pragma unroll
  for (int k = 1; k < 64; k <<= 1) v += __shfl_xor(v, k);
  return v;
}
DEV float rsum16(float v){
  #pragma unroll
  for (int k = 1; k < 16; k <<= 1) v += __shfl_xor(v, k);
  return v;
}
DEV float rmax16(float v){
  #pragma unroll
  for (int k = 1; k < 16; k <<= 1) v = fmaxf(v, __shfl_xor(v, k));
  return v;
}

__global__ void prep_w(const float* __restrict__ Wq, const float* __restrict__ Wk,
                       const float* __restrict__ Wv, const float* __restrict__ Wp,
                       const float* __restrict__ W1, const float* __restrict__ W2,
                       unsigned short* __restrict__ ws){
  int t = blockIdx.x * 256 + threadIdx.x;   // grid covers exactly 786432
  float v;
  if (t < 196608){
    int seg = t >> 16, r = t & 65535;
    int c = r & 255, d = (r >> 8) & 63, h = r >> 14;
    const float* W = (seg == 0) ? Wq : ((seg == 1) ? Wk : Wv);
    v = W[h*16384 + c*64 + d];
  } else if (t < 262144){
    int r = t - 196608; int n = r >> 8, c = r & 255;
    v = Wp[c*256 + n];
  } else if (t < 524288){
    int r = t - 262144; int n = r >> 8, c = r & 255;
    v = W1[c*1024 + n];
  } else {
    int r = t - 524288; int n = r >> 10, k = r & 1023;
    v = W2[k*256 + n];
  }
  ws[t] = f2bf(v);
}

// ---------------- attnproj_k: LN1 + attention + proj + residual --------------
// One 4-wave block per batch element; proven numerics, unchanged from R9.
__global__ __launch_bounds__(256, 2) void attnproj_k(
    const float* __restrict__ x,
    const float* __restrict__ ln1g, const float* __restrict__ ln1b,
    const unsigned short* __restrict__ wqT,
    const unsigned short* __restrict__ wkT,
    const unsigned short* __restrict__ wvT,
    const unsigned short* __restrict__ wpT,
    const float* __restrict__ bpj,
    float* __restrict__ outp)
{
  __shared__ char smb[65536] __attribute__((aligned(16)));
  char* sm = smb;
  const int HLS = 0, QLS = 32768, KLS = 40960, VTLS = 49152, PATLS = 57344;

  const int b = blockIdx.x;
  const float* __restrict__ xb = x + (size_t)b * 16384;
  float* __restrict__ ob = outp + (size_t)b * 16384;
  const int tid = threadIdx.x;
  const int w = tid >> 6, l = tid & 63, m = l & 15, g = l >> 4;
  const v4f zf = {0.f, 0.f, 0.f, 0.f};

  // Phase A: LN1 -> h (bf16, LDS), 16 rows/wave
  {
    f4v lg = *(const f4v*)(ln1g + 4*l);
    f4v lb = *(const f4v*)(ln1b + 4*l);
    #pragma unroll
    for (int rr = 0; rr < 16; ++rr){
      int r = w*16 + rr;
      f4v xv = *(const f4v*)(xb + r*256 + 4*l);
      float s = xv[0]+xv[1]+xv[2]+xv[3];
      float q = xv[0]*xv[0]+xv[1]*xv[1]+xv[2]*xv[2]+xv[3]*xv[3];
      s = rsum64(s); q = rsum64(q);
      float mu = s * (1.f/256.f);
      float rs = rsqrtf(q * (1.f/256.f) - mu*mu + 1e-6f);
      u64 pk = 0;
      #pragma unroll
      for (int j = 0; j < 4; ++j){
        float hv = (xv[j] - mu) * rs * lg[j] + lb[j];
        pk |= (u64)f2bf(hv) << (16*j);
      }
      *(u64*)(sm + HLS + hoff(r, 4*l)) = pk;
    }
  }
  bar();

  // Phase B: attention; sa accumulated in regs
  v4f sa[4][4];
  #pragma unroll
  for (int i = 0; i < 4; ++i){
    #pragma unroll
    for (int j = 0; j < 4; ++j) sa[i][j] = zf;
  }

  #pragma unroll 1
  for (int hh = 0; hh < 4; ++hh){
    // QKV: wave w owns cols w*16..w*16+15 of q,k,v (shared A-fragments)
    {
      const unsigned short* bq = wqT + hh*16384 + (w*16 + m)*256;
      const unsigned short* bk = wkT + hh*16384 + (w*16 + m)*256;
      const unsigned short* bv = wvT + hh*16384 + (w*16 + m)*256;
      v4f qa[4] = {zf,zf,zf,zf}, ka[4] = {zf,zf,zf,zf}, va[4] = {zf,zf,zf,zf};
      #pragma unroll
      for (int ks = 0; ks < 8; ++ks){
        int k0 = ks*32 + 8*g;
        v4i bq4 = *(const v4i*)(bq + k0);
        v4i bk4 = *(const v4i*)(bk + k0);
        v4i bv4 = *(const v4i*)(bv + k0);
        #pragma unroll
        for (int rt = 0; rt < 4; ++rt){
          v4i af = *(const v4i*)(sm + HLS + hoff(rt*16 + m, k0));
          qa[rt] = mfma16(af, bq4, qa[rt]);
          ka[rt] = mfma16(af, bk4, ka[rt]);
          va[rt] = mfma16(af, bv4, va[rt]);
        }
      }
      #pragma unroll
      for (int rt = 0; rt < 4; ++rt){
        qa[rt] = accfence(qa[rt]); ka[rt] = accfence(ka[rt]); va[rt] = accfence(va[rt]);
        #pragma unroll
        for (int j = 0; j < 4; ++j){
          *(unsigned short*)(sm + QLS + koff(rt*16 + 4*g + j, w*16 + m)) = f2bf(qa[rt][j]);
          *(unsigned short*)(sm + KLS + koff(rt*16 + 4*g + j, w*16 + m)) = f2bf(ka[rt][j]);
        }
        *(u64*)(sm + VTLS + koff(w*16 + m, rt*16 + 4*g)) = pack4(va[rt]);  // V^T
      }
    }
    bar();   // bar1: q,k,v^T ready; prev-head PATLS readers done

    // S = Q K^T (stripe rows w*16..+15) -> softmax -> P -> PV -> own PATLS
    {
      v4f s4[4] = {zf,zf,zf,zf};
      #pragma unroll
      for (int ks = 0; ks < 2; ++ks){
        int k0 = ks*32 + 8*g;
        v4i qf = *(const v4i*)(sm + QLS + koff(w*16 + m, k0));
        #pragma unroll
        for (int nt = 0; nt < 4; ++nt){
          v4i kf = *(const v4i*)(sm + KLS + koff(nt*16 + m, k0));
          s4[nt] = mfma16(qf, kf, s4[nt]);
        }
      }
      #pragma unroll
      for (int nt = 0; nt < 4; ++nt) s4[nt] = accfence(s4[nt]);
      float mx[4] = {-3e38f, -3e38f, -3e38f, -3e38f};
      #pragma unroll
      for (int nt = 0; nt < 4; ++nt){
        #pragma unroll
        for (int j = 0; j < 4; ++j){
          int t = w*16 + 4*g + j, ss = nt*16 + m;
          float z = s4[nt][j] * 0.125f;
          z = (ss <= t) ? z : -1e30f;
          s4[nt][j] = z;
          mx[j] = fmaxf(mx[j], z);
        }
      }
      #pragma unroll
      for (int j = 0; j < 4; ++j) mx[j] = rmax16(mx[j]);
      float sum[4] = {0.f, 0.f, 0.f, 0.f};
      #pragma unroll
      for (int nt = 0; nt < 4; ++nt){
        #pragma unroll
        for (int j = 0; j < 4; ++j){
          float p = __expf(s4[nt][j] - mx[j]);
          s4[nt][j] = p;
          sum[j] += p;
        }
      }
      #pragma unroll
      for (int j = 0; j < 4; ++j) sum[j] = 1.f / rsum16(sum[j]);
      #pragma unroll
      for (int nt = 0; nt < 4; ++nt){
        #pragma unroll
        for (int j = 0; j < 4; ++j)
          *(unsigned short*)(sm + PATLS + w*2048 + koff(4*g + j, nt*16 + m)) =
              f2bf(s4[nt][j] * sum[j]);
      }
      v4f av[4] = {zf,zf,zf,zf};
      #pragma unroll
      for (int ks = 0; ks < 2; ++ks){
        int k0 = ks*32 + 8*g;
        v4i pf = *(const v4i*)(sm + PATLS + w*2048 + koff(m, k0));
        #pragma unroll
        for (int nt = 0; nt < 4; ++nt){
          v4i vf = *(const v4i*)(sm + VTLS + koff(nt*16 + m, k0));
          av[nt] = mfma16(pf, vf, av[nt]);
        }
      }
      #pragma unroll
      for (int nt = 0; nt < 4; ++nt) av[nt] = accfence(av[nt]);
      #pragma unroll
      for (int nt = 0; nt < 4; ++nt){
        #pragma unroll
        for (int j = 0; j < 4; ++j)
          *(unsigned short*)(sm + PATLS + w*2048 + koff(4*g + j, nt*16 + m)) =
              f2bf(av[nt][j]);
      }
    }
    bar();   // bar2: att stripes ready

    // proj: sa += att_head @ Wproj[64*hh:, :]; wave w owns cols w*64..w*64+63
    #pragma unroll
    for (int ks = 0; ks < 2; ++ks){
      int k0 = ks*32 + 8*g;
      v4i af2[4];
      #pragma unroll
      for (int rt = 0; rt < 4; ++rt)
        af2[rt] = *(const v4i*)(sm + PATLS + rt*2048 + koff(m, k0));
      #pragma unroll
      for (int nt = 0; nt < 4; ++nt){
        v4i bp = *(const v4i*)(wpT + (w*64 + nt*16 + m)*256 + hh*64 + k0);
        #pragma unroll
        for (int rt = 0; rt < 4; ++rt) sa[rt][nt] = mfma16(af2[rt], bp, sa[rt][nt]);
      }
    }
    // no trailing barrier: PATLS next written after next bar1.
  }

  // Phase C residual: x2 = x + sa + bproj -> f32 in d_out
  {
    #pragma unroll
    for (int i = 0; i < 4; ++i){
      #pragma unroll
      for (int j = 0; j < 4; ++j) sa[i][j] = accfence(sa[i][j]);
    }
    float bp4[4];
    #pragma unroll
    for (int nt = 0; nt < 4; ++nt) bp4[nt] = bpj[w*64 + nt*16 + m];
    #pragma unroll
    for (int rt = 0; rt < 4; ++rt){
      #pragma unroll
      for (int j = 0; j < 4; ++j){
        int row = rt*16 + 4*g + j;
        #pragma unroll
        for (int nt = 0; nt < 4; ++nt){
          int col = w*64 + nt*16 + m;
          ob[row*256 + col] = xb[row*256 + col] + sa[rt][nt][j] + bp4[nt];
        }
      }
    }
  }
}

// ---------------- mlp_k: 2 batch/block (M=128), swapped-operand GEMMs --------
// LDS 128KB dynamic: h2 [128][256] bf16 @0 | act chunk [128][256] bf16 @64K.
// 8 waves; wave w owns 32 N-cols. 4 chunks x (GEMM1, bar, GEMM2, bar).
// A=weights, B=activations: C row-dim (4g+j) = output COLUMN -> per-lane
// outputs are 4 consecutive cols at fixed row: act stores are ds_write_b64,
// final residual is float4 RMW. a1[2][8] + ff[2][8] = 128 VGPR, as R9.
#define MLP_LDS 131072
__global__ __launch_bounds__(512, 1) void mlp_k(
    const float* __restrict__ ln2g, const float* __restrict__ ln2b,
    const unsigned short* __restrict__ w1T,
    const float* __restrict__ b1,
    const unsigned short* __restrict__ w2T,
    const float* __restrict__ b2,
    float* __restrict__ outp)
{
  extern __shared__ char sm[];
  const int HLS = 0, ACT = 65536;
  const int bb = blockIdx.x;               // 2-batch slab
  float* __restrict__ ob = outp + (size_t)bb * 32768;
  const int tid = threadIdx.x;
  const int w = tid >> 6, l = tid & 63, m = l & 15, g = l >> 4;
  const v4f zf = {0.f, 0.f, 0.f, 0.f};

  // LN2 from x2 (f32 in d_out) -> h2 (bf16, LDS); 8 waves x 16 rows = 128
  {
    f4v lg = *(const f4v*)(ln2g + 4*l);
    f4v lb = *(const f4v*)(ln2b + 4*l);
    #pragma unroll
    for (int rr = 0; rr < 16; ++rr){
      int r = w*16 + rr;
      f4v xv = *(const f4v*)(ob + r*256 + 4*l);
      float s = xv[0]+xv[1]+xv[2]+xv[3];
      float q = xv[0]*xv[0]+xv[1]*xv[1]+xv[2]*xv[2]+xv[3]*xv[3];
      s = rsum64(s); q = rsum64(q);
      float mu = s * (1.f/256.f);
      float rs = rsqrtf(q * (1.f/256.f) - mu*mu + 1e-6f);
      u64 pk = 0;
      #pragma unroll
      for (int j = 0; j < 4; ++j){
        float hv = (xv[j] - mu) * rs * lg[j] + lb[j];
        pk |= (u64)f2bf(hv) << (16*j);
      }
      *(u64*)(sm + HLS + hoff(r, 4*l)) = pk;
    }
  }
  bar();

  v4f ff[2][8];                            // [outcol-tile][row-tile]
  #pragma unroll
  for (int i = 0; i < 2; ++i)
    #pragma unroll
    for (int j = 0; j < 8; ++j) ff[i][j] = zf;

  #pragma unroll 1
  for (int ch = 0; ch < 4; ++ch){
    // GEMM1 (A=W1T rows = out-cols, B=h2 rows): a1[oc][rt]
    v4f a1[2][8];
    #pragma unroll
    for (int i = 0; i < 2; ++i)
      #pragma unroll
      for (int j = 0; j < 8; ++j) a1[i][j] = zf;
    const unsigned short* w1a = w1T + (ch*256 + w*32 +      m)*256;
    const unsigned short* w1b = w1T + (ch*256 + w*32 + 16 + m)*256;
    #pragma unroll
    for (int ks = 0; ks < 8; ++ks){
      int k0 = ks*32 + 8*g;
      v4i aw0 = *(const v4i*)(w1a + k0);
      v4i aw1 = *(const v4i*)(w1b + k0);
      #pragma unroll
      for (int rt = 0; rt < 8; ++rt){
        v4i bh = *(const v4i*)(sm + HLS + hoff(rt*16 + m, k0));
        a1[0][rt] = mfma16(aw0, bh, a1[0][rt]);
        a1[1][rt] = mfma16(aw1, bh, a1[1][rt]);
      }
    }
    // bias + relu + packed act store: act[row = rt*16+m][col = w*32+oc*16+4g+j]
    f4v b1f[2];
    #pragma unroll
    for (int oc = 0; oc < 2; ++oc)
      b1f[oc] = *(const f4v*)(b1 + ch*256 + w*32 + oc*16 + 4*g);
    #pragma unroll
    for (int i = 0; i < 2; ++i)
      #pragma unroll
      for (int j = 0; j < 8; ++j) a1[i][j] = accfence(a1[i][j]);
    #pragma unroll
    for (int oc = 0; oc < 2; ++oc){
      #pragma unroll
      for (int rt = 0; rt < 8; ++rt){
        v4f v;
        #pragma unroll
        for (int j = 0; j < 4; ++j) v[j] = fmaxf(a1[oc][rt][j] + b1f[oc][j], 0.f);
        *(u64*)(sm + ACT + hoff(rt*16 + m, w*32 + oc*16 + 4*g)) = pack4(v);
      }
    }
    bar();   // act chunk ready

    // GEMM2 (A=W2T rows = final out-cols, B=act rows): ff[nt][rt]
    const unsigned short* w2a = w2T + (w*32 +      m)*1024 + ch*256;
    const unsigned short* w2b = w2T + (w*32 + 16 + m)*1024 + ch*256;
    #pragma unroll
    for (int ks = 0; ks < 8; ++ks){
      int k0 = ks*32 + 8*g;
      v4i aw0 = *(const v4i*)(w2a + k0);
      v4i aw1 = *(const v4i*)(w2b + k0);
      #pragma unroll
      for (int rt = 0; rt < 8; ++rt){
        v4i bact = *(const v4i*)(sm + ACT + hoff(rt*16 + m, k0));
        ff[0][rt] = mfma16(aw0, bact, ff[0][rt]);
        ff[1][rt] = mfma16(aw1, bact, ff[1][rt]);
      }
    }
    bar();   // protect act before next chunk's GEMM1 overwrite
  }

  // Final: out = x2 + ff + b2, float4 RMW (4 consecutive cols per lane)
  {
    f4v b2f[2];
    #pragma unroll
    for (int nt = 0; nt < 2; ++nt)
      b2f[nt] = *(const f4v*)(b2 + w*32 + nt*16 + 4*g);
    #pragma unroll
    for (int i = 0; i < 2; ++i)
      #pragma unroll
      for (int j = 0; j < 8; ++j) ff[i][j] = accfence(ff[i][j]);
    #pragma unroll
    for (int nt = 0; nt < 2; ++nt){
      #pragma unroll
      for (int rt = 0; rt < 8; ++rt){
        int row = rt*16 + m;
        f4v* p = (f4v*)(ob + row*256 + w*32 + nt*16 + 4*g);
        f4v v = *p;
        #pragma unroll
        for (int j = 0; j < 4; ++j) v[j] += ff[nt][rt][j] + b2f[nt][j];
        *p = v;
      }
    }
  }
}

extern "C" void kernel_launch(void* const* d_in, const int* in_sizes, int n_in,
                              void* d_out, int out_size, void* d_ws, size_t ws_size,
                              hipStream_t stream) {
  const float* x    = (const float*)d_in[0];
  const float* ln1g = (const float*)d_in[1];
  const float* ln1b = (const float*)d_in[2];
  const float* Wq   = (const float*)d_in[3];
  const float* Wk   = (const float*)d_in[4];
  const float* Wv   = (const float*)d_in[5];
  const float* Wp   = (const float*)d_in[6];
  const float* bpj  = (const float*)d_in[7];
  const float* ln2g = (const float*)d_in[8];
  const float* ln2b = (const float*)d_in[9];
  const float* W1   = (const float*)d_in[10];
  const float* b1   = (const float*)d_in[11];
  const float* W2   = (const float*)d_in[12];
  const float* b2   = (const float*)d_in[13];
  unsigned short* ws = (unsigned short*)d_ws;
  float* outp = (float*)d_out;

  hipFuncSetAttribute((const void*)mlp_k,
                      hipFuncAttributeMaxDynamicSharedMemorySize, MLP_LDS);

  prep_w<<<3072, 256, 0, stream>>>(Wq, Wk, Wv, Wp, W1, W2, ws);
  attnproj_k<<<4096, 256, 0, stream>>>(x, ln1g, ln1b,
                                       ws, ws + 65536, ws + 131072, ws + 196608,
                                       bpj, outp);
  mlp_k<<<2048, 512, MLP_LDS, stream>>>(ln2g, ln2b, ws + 262144, b1,
                                        ws + 524288, b2, outp);
}

// Round 14
// 822.369 us; speedup vs baseline: 1.5665x; 1.0468x over previous
//
#include <hip/hip_runtime.h>
#include <hip/hip_bf16.h>

// Fused transformer block as a 3-kernel pipeline:
//   prep_w     : f32 weights -> bf16 transposed in ws (1.5 MB only).
//   attnproj_k : LN1 -> per-head (QKV -> causal softmax -> PV -> proj-accum
//                in regs) -> x2 = x + sa + bproj -> f32 in d_out. Proven R9.
//   mlp_k      : R13's swapped-operand structure widened to 16 waves
//                (1024 thr): same M=128, same 128KB LDS, same 9 barriers,
//                but 4 waves/SIMD instead of 2 -> phase-internal latency
//                hiding doubles. Per-wave stripe 16 out-cols: a1[8]+ff[8]
//                = 64 acc VGPRs (R13 measured 88 total at 32 cols/wave).
// R12 lesson: live set must not grow (spills). R10 lesson: don't add
// barriers. This change does neither.
// ws layout (bf16/ushort): [0,65536) WqT[h][d][c]; [65536,131072) WkT;
// [131072,196608) WvT; [196608,262144) WprojT[n][c]; [262144,524288) W1T[n][c];
// [524288,786432) W2T[n][k].  Requires ws_size >= 1572864 bytes only.

typedef float v4f __attribute__((ext_vector_type(4)));
typedef int   v4i __attribute__((ext_vector_type(4)));
typedef float f4v __attribute__((ext_vector_type(4)));
typedef unsigned long long u64;

#define DEV static __device__ __forceinline__

DEV unsigned short f2bf(float f){
  return __builtin_bit_cast(unsigned short, __float2bfloat16(f));
}

// lgkm-only workgroup barrier: orders LDS traffic, leaves global loads in
// flight. Safe because all cross-wave data in these kernels flows via LDS.
DEV void bar(){
  asm volatile("s_waitcnt lgkmcnt(0)\n\ts_barrier" ::: "memory");
}

// bf16 MFMA via inline asm (layout-safe: consistent per-lane contiguous-8 K).
DEV v4f mfma16(v4i a, v4i b, v4f c){
  asm("v_mfma_f32_16x16x32_bf16 %0, %1, %2, %0" : "+v"(c) : "v"(a), "v"(b));
  return c;
}
DEV v4f accfence(v4f c){
  asm("s_nop 7\n\ts_nop 3" : "+v"(c));
  return c;
}

// Swizzled LDS byte offsets (XOR row bits into 16B-granule bits).
DEV int hoff(int r, int c){ return r*512 + ((c*2) ^ ((r & 7) << 4)); }  // [*][256] bf16
DEV int koff(int r, int c){ return r*128 + ((c*2) ^ ((r & 7) << 4)); }  // [*][64]  bf16

DEV u64 pack4(v4f v){
  return (u64)f2bf(v[0]) | ((u64)f2bf(v[1]) << 16)
       | ((u64)f2bf(v[2]) << 32) | ((u64)f2bf(v[3]) << 48);
}

DEV float rsum64(float v){
  #pragma unroll
  for (int k = 1; k < 64; k <<= 1) v += __shfl_xor(v, k);
  return v;
}
DEV float rsum16(float v){
  #pragma unroll
  for (int k = 1; k < 16; k <<= 1) v += __shfl_xor(v, k);
  return v;
}
DEV float rmax16(float v){
  #pragma unroll
  for (int k = 1; k < 16; k <<= 1) v = fmaxf(v, __shfl_xor(v, k));
  return v;
}

__global__ void prep_w(const float* __restrict__ Wq, const float* __restrict__ Wk,
                       const float* __restrict__ Wv, const float* __restrict__ Wp,
                       const float* __restrict__ W1, const float* __restrict__ W2,
                       unsigned short* __restrict__ ws){
  int t = blockIdx.x * 256 + threadIdx.x;   // grid covers exactly 786432
  float v;
  if (t < 196608){
    int seg = t >> 16, r = t & 65535;
    int c = r & 255, d = (r >> 8) & 63, h = r >> 14;
    const float* W = (seg == 0) ? Wq : ((seg == 1) ? Wk : Wv);
    v = W[h*16384 + c*64 + d];
  } else if (t < 262144){
    int r = t - 196608; int n = r >> 8, c = r & 255;
    v = Wp[c*256 + n];
  } else if (t < 524288){
    int r = t - 262144; int n = r >> 8, c = r & 255;
    v = W1[c*1024 + n];
  } else {
    int r = t - 524288; int n = r >> 10, k = r & 1023;
    v = W2[k*256 + n];
  }
  ws[t] = f2bf(v);
}

// ---------------- attnproj_k: LN1 + attention + proj + residual --------------
// One 4-wave block per batch element; proven numerics, unchanged from R9.
__global__ __launch_bounds__(256, 2) void attnproj_k(
    const float* __restrict__ x,
    const float* __restrict__ ln1g, const float* __restrict__ ln1b,
    const unsigned short* __restrict__ wqT,
    const unsigned short* __restrict__ wkT,
    const unsigned short* __restrict__ wvT,
    const unsigned short* __restrict__ wpT,
    const float* __restrict__ bpj,
    float* __restrict__ outp)
{
  __shared__ char smb[65536] __attribute__((aligned(16)));
  char* sm = smb;
  const int HLS = 0, QLS = 32768, KLS = 40960, VTLS = 49152, PATLS = 57344;

  const int b = blockIdx.x;
  const float* __restrict__ xb = x + (size_t)b * 16384;
  float* __restrict__ ob = outp + (size_t)b * 16384;
  const int tid = threadIdx.x;
  const int w = tid >> 6, l = tid & 63, m = l & 15, g = l >> 4;
  const v4f zf = {0.f, 0.f, 0.f, 0.f};

  // Phase A: LN1 -> h (bf16, LDS), 16 rows/wave
  {
    f4v lg = *(const f4v*)(ln1g + 4*l);
    f4v lb = *(const f4v*)(ln1b + 4*l);
    #pragma unroll
    for (int rr = 0; rr < 16; ++rr){
      int r = w*16 + rr;
      f4v xv = *(const f4v*)(xb + r*256 + 4*l);
      float s = xv[0]+xv[1]+xv[2]+xv[3];
      float q = xv[0]*xv[0]+xv[1]*xv[1]+xv[2]*xv[2]+xv[3]*xv[3];
      s = rsum64(s); q = rsum64(q);
      float mu = s * (1.f/256.f);
      float rs = rsqrtf(q * (1.f/256.f) - mu*mu + 1e-6f);
      u64 pk = 0;
      #pragma unroll
      for (int j = 0; j < 4; ++j){
        float hv = (xv[j] - mu) * rs * lg[j] + lb[j];
        pk |= (u64)f2bf(hv) << (16*j);
      }
      *(u64*)(sm + HLS + hoff(r, 4*l)) = pk;
    }
  }
  bar();

  // Phase B: attention; sa accumulated in regs
  v4f sa[4][4];
  #pragma unroll
  for (int i = 0; i < 4; ++i){
    #pragma unroll
    for (int j = 0; j < 4; ++j) sa[i][j] = zf;
  }

  #pragma unroll 1
  for (int hh = 0; hh < 4; ++hh){
    // QKV: wave w owns cols w*16..w*16+15 of q,k,v (shared A-fragments)
    {
      const unsigned short* bq = wqT + hh*16384 + (w*16 + m)*256;
      const unsigned short* bk = wkT + hh*16384 + (w*16 + m)*256;
      const unsigned short* bv = wvT + hh*16384 + (w*16 + m)*256;
      v4f qa[4] = {zf,zf,zf,zf}, ka[4] = {zf,zf,zf,zf}, va[4] = {zf,zf,zf,zf};
      #pragma unroll
      for (int ks = 0; ks < 8; ++ks){
        int k0 = ks*32 + 8*g;
        v4i bq4 = *(const v4i*)(bq + k0);
        v4i bk4 = *(const v4i*)(bk + k0);
        v4i bv4 = *(const v4i*)(bv + k0);
        #pragma unroll
        for (int rt = 0; rt < 4; ++rt){
          v4i af = *(const v4i*)(sm + HLS + hoff(rt*16 + m, k0));
          qa[rt] = mfma16(af, bq4, qa[rt]);
          ka[rt] = mfma16(af, bk4, ka[rt]);
          va[rt] = mfma16(af, bv4, va[rt]);
        }
      }
      #pragma unroll
      for (int rt = 0; rt < 4; ++rt){
        qa[rt] = accfence(qa[rt]); ka[rt] = accfence(ka[rt]); va[rt] = accfence(va[rt]);
        #pragma unroll
        for (int j = 0; j < 4; ++j){
          *(unsigned short*)(sm + QLS + koff(rt*16 + 4*g + j, w*16 + m)) = f2bf(qa[rt][j]);
          *(unsigned short*)(sm + KLS + koff(rt*16 + 4*g + j, w*16 + m)) = f2bf(ka[rt][j]);
        }
        *(u64*)(sm + VTLS + koff(w*16 + m, rt*16 + 4*g)) = pack4(va[rt]);  // V^T
      }
    }
    bar();   // bar1: q,k,v^T ready; prev-head PATLS readers done

    // S = Q K^T (stripe rows w*16..+15) -> softmax -> P -> PV -> own PATLS
    {
      v4f s4[4] = {zf,zf,zf,zf};
      #pragma unroll
      for (int ks = 0; ks < 2; ++ks){
        int k0 = ks*32 + 8*g;
        v4i qf = *(const v4i*)(sm + QLS + koff(w*16 + m, k0));
        #pragma unroll
        for (int nt = 0; nt < 4; ++nt){
          v4i kf = *(const v4i*)(sm + KLS + koff(nt*16 + m, k0));
          s4[nt] = mfma16(qf, kf, s4[nt]);
        }
      }
      #pragma unroll
      for (int nt = 0; nt < 4; ++nt) s4[nt] = accfence(s4[nt]);
      float mx[4] = {-3e38f, -3e38f, -3e38f, -3e38f};
      #pragma unroll
      for (int nt = 0; nt < 4; ++nt){
        #pragma unroll
        for (int j = 0; j < 4; ++j){
          int t = w*16 + 4*g + j, ss = nt*16 + m;
          float z = s4[nt][j] * 0.125f;
          z = (ss <= t) ? z : -1e30f;
          s4[nt][j] = z;
          mx[j] = fmaxf(mx[j], z);
        }
      }
      #pragma unroll
      for (int j = 0; j < 4; ++j) mx[j] = rmax16(mx[j]);
      float sum[4] = {0.f, 0.f, 0.f, 0.f};
      #pragma unroll
      for (int nt = 0; nt < 4; ++nt){
        #pragma unroll
        for (int j = 0; j < 4; ++j){
          float p = __expf(s4[nt][j] - mx[j]);
          s4[nt][j] = p;
          sum[j] += p;
        }
      }
      #pragma unroll
      for (int j = 0; j < 4; ++j) sum[j] = 1.f / rsum16(sum[j]);
      #pragma unroll
      for (int nt = 0; nt < 4; ++nt){
        #pragma unroll
        for (int j = 0; j < 4; ++j)
          *(unsigned short*)(sm + PATLS + w*2048 + koff(4*g + j, nt*16 + m)) =
              f2bf(s4[nt][j] * sum[j]);
      }
      v4f av[4] = {zf,zf,zf,zf};
      #pragma unroll
      for (int ks = 0; ks < 2; ++ks){
        int k0 = ks*32 + 8*g;
        v4i pf = *(const v4i*)(sm + PATLS + w*2048 + koff(m, k0));
        #pragma unroll
        for (int nt = 0; nt < 4; ++nt){
          v4i vf = *(const v4i*)(sm + VTLS + koff(nt*16 + m, k0));
          av[nt] = mfma16(pf, vf, av[nt]);
        }
      }
      #pragma unroll
      for (int nt = 0; nt < 4; ++nt) av[nt] = accfence(av[nt]);
      #pragma unroll
      for (int nt = 0; nt < 4; ++nt){
        #pragma unroll
        for (int j = 0; j < 4; ++j)
          *(unsigned short*)(sm + PATLS + w*2048 + koff(4*g + j, nt*16 + m)) =
              f2bf(av[nt][j]);
      }
    }
    bar();   // bar2: att stripes ready

    // proj: sa += att_head @ Wproj[64*hh:, :]; wave w owns cols w*64..w*64+63
    #pragma unroll
    for (int ks = 0; ks < 2; ++ks){
      int k0 = ks*32 + 8*g;
      v4i af2[4];
      #pragma unroll
      for (int rt = 0; rt < 4; ++rt)
        af2[rt] = *(const v4i*)(sm + PATLS + rt*2048 + koff(m, k0));
      #pragma unroll
      for (int nt = 0; nt < 4; ++nt){
        v4i bp = *(const v4i*)(wpT + (w*64 + nt*16 + m)*256 + hh*64 + k0);
        #pragma unroll
        for (int rt = 0; rt < 4; ++rt) sa[rt][nt] = mfma16(af2[rt], bp, sa[rt][nt]);
      }
    }
    // no trailing barrier: PATLS next written after next bar1.
  }

  // Phase C residual: x2 = x + sa + bproj -> f32 in d_out
  {
    #pragma unroll
    for (int i = 0; i < 4; ++i){
      #pragma unroll
      for (int j = 0; j < 4; ++j) sa[i][j] = accfence(sa[i][j]);
    }
    float bp4[4];
    #pragma unroll
    for (int nt = 0; nt < 4; ++nt) bp4[nt] = bpj[w*64 + nt*16 + m];
    #pragma unroll
    for (int rt = 0; rt < 4; ++rt){
      #pragma unroll
      for (int j = 0; j < 4; ++j){
        int row = rt*16 + 4*g + j;
        #pragma unroll
        for (int nt = 0; nt < 4; ++nt){
          int col = w*64 + nt*16 + m;
          ob[row*256 + col] = xb[row*256 + col] + sa[rt][nt][j] + bp4[nt];
        }
      }
    }
  }
}

// ---------------- mlp_k: 2 batch/block (M=128), 16 waves, swapped ops --------
// LDS 128KB dynamic: h2 [128][256] bf16 @0 | act chunk [128][256] bf16 @64K.
// 16 waves; wave w owns 16 out-cols per chunk. 4 chunks x (GEMM1, bar,
// GEMM2, bar) = 9 lgkm barriers (same as R13). 4 waves/SIMD during phases.
#define MLP_LDS 131072
__global__ __launch_bounds__(1024, 1) void mlp_k(
    const float* __restrict__ ln2g, const float* __restrict__ ln2b,
    const unsigned short* __restrict__ w1T,
    const float* __restrict__ b1,
    const unsigned short* __restrict__ w2T,
    const float* __restrict__ b2,
    float* __restrict__ outp)
{
  extern __shared__ char sm[];
  const int HLS = 0, ACT = 65536;
  const int bb = blockIdx.x;               // 2-batch slab
  float* __restrict__ ob = outp + (size_t)bb * 32768;
  const int tid = threadIdx.x;
  const int w = tid >> 6, l = tid & 63, m = l & 15, g = l >> 4;
  const v4f zf = {0.f, 0.f, 0.f, 0.f};

  // LN2 from x2 (f32 in d_out) -> h2 (bf16, LDS); 16 waves x 8 rows = 128
  {
    f4v lg = *(const f4v*)(ln2g + 4*l);
    f4v lb = *(const f4v*)(ln2b + 4*l);
    #pragma unroll
    for (int rr = 0; rr < 8; ++rr){
      int r = w*8 + rr;
      f4v xv = *(const f4v*)(ob + r*256 + 4*l);
      float s = xv[0]+xv[1]+xv[2]+xv[3];
      float q = xv[0]*xv[0]+xv[1]*xv[1]+xv[2]*xv[2]+xv[3]*xv[3];
      s = rsum64(s); q = rsum64(q);
      float mu = s * (1.f/256.f);
      float rs = rsqrtf(q * (1.f/256.f) - mu*mu + 1e-6f);
      u64 pk = 0;
      #pragma unroll
      for (int j = 0; j < 4; ++j){
        float hv = (xv[j] - mu) * rs * lg[j] + lb[j];
        pk |= (u64)f2bf(hv) << (16*j);
      }
      *(u64*)(sm + HLS + hoff(r, 4*l)) = pk;
    }
  }
  bar();

  v4f ff[8];                               // out-cols w*16..+15, 8 row-tiles
  #pragma unroll
  for (int j = 0; j < 8; ++j) ff[j] = zf;

  #pragma unroll 1
  for (int ch = 0; ch < 4; ++ch){
    // GEMM1 (A=W1T rows = out-cols, B=h2 rows): a1[rt]
    v4f a1[8];
    #pragma unroll
    for (int j = 0; j < 8; ++j) a1[j] = zf;
    const unsigned short* w1a = w1T + (ch*256 + w*16 + m)*256;
    #pragma unroll
    for (int ks = 0; ks < 8; ++ks){
      int k0 = ks*32 + 8*g;
      v4i aw0 = *(const v4i*)(w1a + k0);
      #pragma unroll
      for (int rt = 0; rt < 8; ++rt){
        v4i bh = *(const v4i*)(sm + HLS + hoff(rt*16 + m, k0));
        a1[rt] = mfma16(aw0, bh, a1[rt]);
      }
    }
    // bias + relu + packed act store: act[row = rt*16+m][col = w*16+4g+j]
    f4v b1f = *(const f4v*)(b1 + ch*256 + w*16 + 4*g);
    #pragma unroll
    for (int j = 0; j < 8; ++j) a1[j] = accfence(a1[j]);
    #pragma unroll
    for (int rt = 0; rt < 8; ++rt){
      v4f v;
      #pragma unroll
      for (int j = 0; j < 4; ++j) v[j] = fmaxf(a1[rt][j] + b1f[j], 0.f);
      *(u64*)(sm + ACT + hoff(rt*16 + m, w*16 + 4*g)) = pack4(v);
    }
    bar();   // act chunk ready

    // GEMM2 (A=W2T rows = final out-cols, B=act rows): ff[rt]
    const unsigned short* w2a = w2T + (w*16 + m)*1024 + ch*256;
    #pragma unroll
    for (int ks = 0; ks < 8; ++ks){
      int k0 = ks*32 + 8*g;
      v4i aw0 = *(const v4i*)(w2a + k0);
      #pragma unroll
      for (int rt = 0; rt < 8; ++rt){
        v4i bact = *(const v4i*)(sm + ACT + hoff(rt*16 + m, k0));
        ff[rt] = mfma16(aw0, bact, ff[rt]);
      }
    }
    bar();   // protect act before next chunk's GEMM1 overwrite
  }

  // Final: out = x2 + ff + b2, float4 RMW (4 consecutive cols per lane)
  {
    f4v b2f = *(const f4v*)(b2 + w*16 + 4*g);
    #pragma unroll
    for (int j = 0; j < 8; ++j) ff[j] = accfence(ff[j]);
    #pragma unroll
    for (int rt = 0; rt < 8; ++rt){
      int row = rt*16 + m;
      f4v* p = (f4v*)(ob + row*256 + w*16 + 4*g);
      f4v v = *p;
      #pragma unroll
      for (int j = 0; j < 4; ++j) v[j] += ff[rt][j] + b2f[j];
      *p = v;
    }
  }
}

extern "C" void kernel_launch(void* const* d_in, const int* in_sizes, int n_in,
                              void* d_out, int out_size, void* d_ws, size_t ws_size,
                              hipStream_t stream) {
  const float* x    = (const float*)d_in[0];
  const float* ln1g = (const float*)d_in[1];
  const float* ln1b = (const float*)d_in[2];
  const float* Wq   = (const float*)d_in[3];
  const float* Wk   = (const float*)d_in[4];
  const float* Wv   = (const float*)d_in[5];
  const float* Wp   = (const float*)d_in[6];
  const float* bpj  = (const float*)d_in[7];
  const float* ln2g = (const float*)d_in[8];
  const float* ln2b = (const float*)d_in[9];
  const float* W1   = (const float*)d_in[10];
  const float* b1   = (const float*)d_in[11];
  const float* W2   = (const float*)d_in[12];
  const float* b2   = (const float*)d_in[13];
  unsigned short* ws = (unsigned short*)d_ws;
  float* outp = (float*)d_out;

  hipFuncSetAttribute((const void*)mlp_k,
                      hipFuncAttributeMaxDynamicSharedMemorySize, MLP_LDS);

  prep_w<<<3072, 256, 0, stream>>>(Wq, Wk, Wv, Wp, W1, W2, ws);
  attnproj_k<<<4096, 256, 0, stream>>>(x, ln1g, ln1b,
                                       ws, ws + 65536, ws + 131072, ws + 196608,
                                       bpj, outp);
  mlp_k<<<2048, 1024, MLP_LDS, stream>>>(ln2g, ln2b, ws + 262144, b1,
                                         ws + 524288, b2, outp);
}